// Round 13
// baseline (370.417 us; speedup 1.0000x reference)
//
#include <hip/hip_runtime.h>
#include <hip/hip_bf16.h>

// ---------------------------------------------------------------------------
// Sizes (fixed for this problem): N=100000 (mult of 32), E=1600000, G=512
#define F_IN 53
#define D1   128
#define D2   64
#define D3   128   // 2*D2
#define H1SZ 512
#define H2SZ 256

#define BUKSZ   256          // nodes per bucket (bucket = dst >> 8)
#define BUKMAX  512          // max buckets supported (N <= 131072)
#define CAP     5120         // tmp capacity per bucket (avg fill ~4100)
#define PART_CH 4096         // edges per part block (16 per thread)

// v_src[k] = sum_c gat_w[k][c] * att_src[c]  (and same for dst)
__global__ void k_vecproj(const float* __restrict__ gat_w,
                          const float* __restrict__ att_src,
                          const float* __restrict__ att_dst,
                          float* __restrict__ v_src, float* __restrict__ v_dst) {
    int k = threadIdx.x;  // 0..63
    float as = 0.f, ad = 0.f;
    #pragma unroll
    for (int c = 0; c < D2; ++c) {
        float w = gat_w[k * D2 + c];
        as = fmaf(w, att_src[c], as);
        ad = fmaf(w, att_dst[c], ad);
    }
    v_src[k] = as;
    v_dst[k] = ad;
}

// ---- fused: node embedding | edge bucket partition | graph bounds ----------
// Embed path is now BARRIER-FREE: dense1 reads x via wave-uniform SCALAR loads
// (readfirstlane node index -> s_load, scalar pipe), eliminating the xs LDS
// staging + its barrier + 104 LDS broadcasts/wave. h1/h2 stay wave-local LDS.
__global__ __launch_bounds__(256) void k_fused(const float* __restrict__ x,
                                               const float* __restrict__ w1,
                                               const float* __restrict__ b1,
                                               const float* __restrict__ w2,
                                               const float* __restrict__ b2,
                                               const float* __restrict__ gat_w,
                                               const float* __restrict__ v_src,
                                               const float* __restrict__ v_dst,
                                               float* __restrict__ hp,
                                               float* __restrict__ a_s,
                                               float* __restrict__ a_d,
                                               const int* __restrict__ ei,
                                               int* __restrict__ gcount,
                                               int2* __restrict__ tmp,
                                               const int* __restrict__ batch,
                                               int* __restrict__ gstart,
                                               int N, int E, int NBUK, int G,
                                               int embB, int partB) {
    __shared__ __align__(16) union {
        struct { float buf[32][64]; float h1s[32][D1]; } e;  // 8 + 16 KB
        int hist[BUKMAX];
    } sm;
    int tid = threadIdx.x;
    int bid = blockIdx.x;

    if (bid >= embB) {
        if (bid < embB + partB) {
            // ---------------- edge bucket partition ----------------
            for (int i = tid; i < NBUK; i += 256) sm.hist[i] = 0;
            __syncthreads();
            int k0 = (bid - embB) * PART_CH;
            int ss[16], dd[16];
            #pragma unroll
            for (int i = 0; i < 16; ++i) {
                int k = k0 + i * 256 + tid;
                if (k < E) {
                    ss[i] = ei[k];
                    dd[i] = ei[E + k];
                    atomicAdd(&sm.hist[dd[i] >> 8], 1);
                } else {
                    dd[i] = -1;
                }
            }
            __syncthreads();
            for (int b = tid; b < NBUK; b += 256) {
                int c = sm.hist[b];
                if (c > 0) sm.hist[b] = b * CAP + atomicAdd(&gcount[b], c);
            }
            __syncthreads();
            #pragma unroll
            for (int i = 0; i < 16; ++i) {
                if (dd[i] >= 0) {
                    int b = dd[i] >> 8;
                    int pos = atomicAdd(&sm.hist[b], 1);
                    if (pos < (b + 1) * CAP) tmp[pos] = make_int2(ss[i], dd[i]);
                }
            }
        } else {
            // ---------------- graph bounds (batch sorted) ----------------
            int n = (bid - embB - partB) * 256 + tid;
            if (n < N) {
                int b = batch[n];
                if (n == 0) {
                    for (int g = 0; g <= b; ++g) gstart[g] = 0;
                } else {
                    int pb = batch[n - 1];
                    for (int g = pb + 1; g <= b; ++g) gstart[g] = n;
                }
                if (n == N - 1) {
                    for (int g = b + 1; g <= G; ++g) gstart[g] = N;
                }
            }
        }
        return;
    }

    // ---------------- fused node embedding (barrier-free) ----------------
    int n0 = bid * 32;                // N divisible by 32
    int c = tid & 63, grp = tid >> 6;
    int nb = __builtin_amdgcn_readfirstlane(grp * 8);  // wave's 8 nodes (SGPR)
    // dense1: h1 = relu(x@w1+b1); cols (c, c+64) x 8 nodes; x via scalar pipe
    {
        float acc0[8], acc1[8];
        float bb0 = b1[c], bb1 = b1[c + 64];
        #pragma unroll
        for (int j = 0; j < 8; ++j) { acc0[j] = bb0; acc1[j] = bb1; }
        const float* xr = x + (size_t)(n0 + nb) * F_IN;   // uniform base
        #pragma unroll 1
        for (int k = 0; k < F_IN; ++k) {
            float wA = w1[k * D1 + c];
            float wB = w1[k * D1 + c + 64];
            #pragma unroll
            for (int j = 0; j < 8; ++j) {
                float xv = xr[j * F_IN + k];   // wave-uniform -> s_load
                acc0[j] = fmaf(xv, wA, acc0[j]);
                acc1[j] = fmaf(xv, wB, acc1[j]);
            }
        }
        #pragma unroll
        for (int j = 0; j < 8; ++j) {
            sm.e.h1s[nb + j][c]      = fmaxf(acc0[j], 0.f);
            sm.e.h1s[nb + j][c + 64] = fmaxf(acc1[j], 0.f);
        }
    }
    // dense2: h2 = relu(h1@w2+b2); col c x 8 nodes, K=128 (wave-local rows)
    float h2v[8];
    {
        float bb = b2[c];
        #pragma unroll
        for (int j = 0; j < 8; ++j) h2v[j] = bb;
        #pragma unroll 1
        for (int kc = 0; kc < 32; ++kc) {
            int k4 = kc * 4;
            float w0 = w2[(k4 + 0) * D2 + c];
            float w1v = w2[(k4 + 1) * D2 + c];
            float w2v = w2[(k4 + 2) * D2 + c];
            float w3v = w2[(k4 + 3) * D2 + c];
            #pragma unroll
            for (int j = 0; j < 8; ++j) {
                float4 hv = *reinterpret_cast<const float4*>(&sm.e.h1s[nb + j][k4]);
                h2v[j] = fmaf(hv.x, w0, h2v[j]);
                h2v[j] = fmaf(hv.y, w1v, h2v[j]);
                h2v[j] = fmaf(hv.z, w2v, h2v[j]);
                h2v[j] = fmaf(hv.w, w3v, h2v[j]);
            }
        }
        #pragma unroll
        for (int j = 0; j < 8; ++j) {
            float v = fmaxf(h2v[j], 0.f);
            h2v[j] = v;
            sm.e.buf[nb + j][c] = v;
        }
    }
    // a_s = h2 . v_src ; a_d = h2 . v_dst  (wave shuffle reduce; lane == c)
    {
        float vs = v_src[c], vd = v_dst[c];
        #pragma unroll
        for (int j = 0; j < 8; ++j) {
            float ps = h2v[j] * vs, pd = h2v[j] * vd;
            #pragma unroll
            for (int off = 32; off; off >>= 1) {
                ps += __shfl_down(ps, off);
                pd += __shfl_down(pd, off);
            }
            if (c == 0) { int n = n0 + nb + j; a_s[n] = ps; a_d[n] = pd; }
        }
    }
    // hp = h2 @ gat_w; col c x 8 nodes, K=64 (wave-local buf rows)
    {
        float acc[8];
        #pragma unroll
        for (int j = 0; j < 8; ++j) acc[j] = 0.f;
        #pragma unroll 1
        for (int kc = 0; kc < 16; ++kc) {
            int k4 = kc * 4;
            float w0 = gat_w[(k4 + 0) * D2 + c];
            float w1v = gat_w[(k4 + 1) * D2 + c];
            float w2v = gat_w[(k4 + 2) * D2 + c];
            float w3v = gat_w[(k4 + 3) * D2 + c];
            #pragma unroll
            for (int j = 0; j < 8; ++j) {
                float4 hv = *reinterpret_cast<const float4*>(&sm.e.buf[nb + j][k4]);
                acc[j] = fmaf(hv.x, w0, acc[j]);
                acc[j] = fmaf(hv.y, w1v, acc[j]);
                acc[j] = fmaf(hv.z, w2v, acc[j]);
                acc[j] = fmaf(hv.w, w3v, acc[j]);
            }
        }
        #pragma unroll
        for (int j = 0; j < 8; ++j)
            hp[(size_t)(n0 + nb + j) * D2 + c] = acc[j];
    }
}

// ---- CSR build: one block per bucket; inline prefix over gcount ------------
__global__ __launch_bounds__(256) void k_build(const int2* __restrict__ tmp,
                                               const int* __restrict__ gcount,
                                               int* __restrict__ offs,
                                               int* __restrict__ degi,
                                               float* __restrict__ dinv,
                                               int* __restrict__ csr_src, int N) {
    __shared__ int ldeg[256];
    __shared__ int lsc[256];
    __shared__ int lcur[256];
    __shared__ int pref[256];
    int tid = threadIdx.x;
    int b = blockIdx.x;
    int n0 = b * BUKSZ;
    int nvalid = min(BUKSZ, N - n0);
    int cnt = min(gcount[b], CAP);
    // inline exclusive prefix: sum_{i<b} min(gcount[i],CAP)  (b <= 512)
    int acc = 0;
    for (int i = tid; i < b; i += 256) acc += min(gcount[i], CAP);
    pref[tid] = acc;
    ldeg[tid] = 0;
    __syncthreads();
    #pragma unroll
    for (int off = 128; off; off >>= 1) {
        if (tid < off) pref[tid] += pref[tid + off];
        __syncthreads();
    }
    int base = pref[0] + n0;   // edges before + self-loops before
    for (int i = tid; i < cnt; i += 256) {
        int2 e = tmp[b * CAP + i];
        atomicAdd(&ldeg[e.y & 255], 1);
    }
    __syncthreads();
    int d = (tid < nvalid) ? (ldeg[tid] + 1) : 0;   // +1 self-loop
    lsc[tid] = d;
    __syncthreads();
    #pragma unroll
    for (int off = 1; off < 256; off <<= 1) {
        int u = (tid >= off) ? lsc[tid - off] : 0;
        __syncthreads();
        lsc[tid] += u;
        __syncthreads();
    }
    int excl = lsc[tid] - d;
    if (tid < nvalid) {
        int n = n0 + tid;
        offs[n] = base + excl;
        degi[n] = d;
        dinv[n] = rsqrtf((float)d);
        lcur[tid] = excl;
    }
    __syncthreads();
    for (int i = tid; i < cnt; i += 256) {
        int2 e = tmp[b * CAP + i];
        int nl = e.y & 255;
        int r = atomicAdd(&lcur[nl], 1);
        csr_src[base + r] = e.x;
    }
    __syncthreads();
    if (tid < nvalid) {
        int r = atomicAdd(&lcur[tid], 1);
        csr_src[base + r] = n0 + tid;   // self-loop
    }
}

// ---- GAT pull: softmax in regs; alpha AND src indices cached in LDS --------
// hscaled[n] = dinv[n] * relu(sum alpha*hp[src] + gat_b)
__global__ __launch_bounds__(256) void k_gat(const int* __restrict__ csr_src,
                                             const int* __restrict__ offs,
                                             const int* __restrict__ degi,
                                             const float* __restrict__ a_s,
                                             const float* __restrict__ a_d,
                                             const float* __restrict__ hp,
                                             const float* __restrict__ gat_b,
                                             const float* __restrict__ dinv,
                                             float* __restrict__ hscaled, int N) {
    __shared__ float ac[4][128];
    __shared__ int   si[4][128];
    int wv = threadIdx.x >> 6, lane = threadIdx.x & 63;
    int node = blockIdx.x * 4 + wv;
    if (node >= N) return;   // N%4==0 -> never taken; no barriers below
    int start = offs[node], deg = degi[node];
    int dcap = min(deg, 128);
    float adn = a_d[node];
    // phase A: lane-parallel online softmax stats; stash raw e + src in LDS
    float m = -1e30f, ssum = 0.f;
    for (int p = lane; p < deg; p += 64) {
        int s = csr_src[start + p];
        float e = a_s[s] + adn;
        e = (e > 0.f) ? e : 0.2f * e;
        if (p < 128) { ac[wv][p] = e; si[wv][p] = s; }
        float mn = fmaxf(m, e);
        ssum = ssum * __expf(m - mn) + __expf(e - mn);
        m = mn;
    }
    #pragma unroll
    for (int off = 32; off; off >>= 1) {
        float om = __shfl_xor(m, off);
        float os = __shfl_xor(ssum, off);
        float mn = fmaxf(m, om);
        ssum = ssum * __expf(m - mn) + os * __expf(om - mn);
        m = mn;
    }
    float rinv = 1.0f / ssum;
    // convert stashed e -> alpha (same lane wrote p=lane and p=lane+64)
    if (lane < dcap)      ac[wv][lane]      = __expf(ac[wv][lane] - m) * rinv;
    if (lane + 64 < dcap) ac[wv][lane + 64] = __expf(ac[wv][lane + 64] - m) * rinv;
    // phase B: 16-deep fully-predicated weighted gather, indices from LDS
    float acc = 0.f;
    for (int pp = 0; pp < dcap; pp += 16) {
        int s[16]; float w[16];
        #pragma unroll
        for (int i = 0; i < 16; ++i) {
            int q = pp + i;
            int qc = (q < dcap) ? q : (dcap - 1);
            s[i] = si[wv][qc];
            w[i] = (q < dcap) ? ac[wv][q] : 0.f;
        }
        float v[16];
        #pragma unroll
        for (int i = 0; i < 16; ++i) v[i] = hp[(size_t)s[i] * D2 + lane];
        #pragma unroll
        for (int i = 0; i < 16; ++i) acc = fmaf(w[i], v[i], acc);
    }
    for (int p = 128; p < deg; ++p) {   // deg > 128 overflow (essentially never)
        int s = csr_src[start + p];
        float e = a_s[s] + adn;
        e = (e > 0.f) ? e : 0.2f * e;
        acc = fmaf(__expf(e - m) * rinv, hp[(size_t)s * D2 + lane], acc);
    }
    hscaled[(size_t)node * D2 + lane] = dinv[node] * fmaxf(acc + gat_b[lane], 0.f);
}

// ---- GCN pull: hagg[n] = dinv[n]*sum hscaled[src]; 16-deep predicated ------
__global__ __launch_bounds__(256) void k_gcn(const int* __restrict__ csr_src,
                                             const int* __restrict__ offs,
                                             const int* __restrict__ degi,
                                             const float* __restrict__ dinv,
                                             const float* __restrict__ hscaled,
                                             float* __restrict__ hagg, int N) {
    int node = blockIdx.x * 4 + (threadIdx.x >> 6);
    int lane = threadIdx.x & 63;
    if (node >= N) return;
    int start = offs[node], deg = degi[node];
    float acc = 0.f;
    for (int pp = 0; pp < deg; pp += 16) {
        int s[16];
        #pragma unroll
        for (int i = 0; i < 16; ++i) {
            int q = pp + i;
            int qc = (q < deg) ? q : (deg - 1);
            s[i] = csr_src[start + qc];
        }
        float v[16];
        #pragma unroll
        for (int i = 0; i < 16; ++i) v[i] = hscaled[(size_t)s[i] * D2 + lane];
        #pragma unroll
        for (int i = 0; i < 16; ++i) acc += (pp + i < deg) ? v[i] : 0.f;
    }
    hagg[(size_t)node * D2 + lane] = acc * dinv[node];
}

// per-graph fused GEMM [*,64]@[64,128]+bias+relu + max-pool
// 512 thr: LDS-staged 16-node chunks, col=tid&127, 4 nodes/thread, float4 K
__global__ __launch_bounds__(512) void k_pool(const float* __restrict__ hagg,
                                              const float* __restrict__ gcn_w,
                                              const float* __restrict__ gcn_b,
                                              const int* __restrict__ gstart,
                                              float* __restrict__ g) {
    __shared__ float ws[D2 * D3];                 // 32 KB
    __shared__ __align__(16) float rows[16 * D2]; // 4 KB
    __shared__ float red[512];
    int tid = threadIdx.x;
    int gi = blockIdx.x;
    for (int i = tid; i < D2 * D3; i += 512) ws[i] = gcn_w[i];
    int ns = gstart[gi], ne = gstart[gi + 1];
    int col = tid & 127, grp = tid >> 7;   // 4 groups x 4 nodes
    float bias = gcn_b[col];
    float runmax = 0.f;   // relu floor; also handles empty graphs
    for (int base = ns; base < ne; base += 16) {
        int cnt = min(16, ne - base);
        __syncthreads();   // rows reuse + (first iter) ws ready
        for (int i = tid; i < cnt * D2; i += 512)
            rows[i] = hagg[(size_t)base * D2 + i];
        __syncthreads();
        int nb = grp * 4;
        float a0 = bias, a1 = bias, a2 = bias, a3 = bias;
        #pragma unroll 4
        for (int kc = 0; kc < 16; ++kc) {
            int k4 = kc * 4;
            float w0 = ws[(k4 + 0) * D3 + col];
            float w1v = ws[(k4 + 1) * D3 + col];
            float w2v = ws[(k4 + 2) * D3 + col];
            float w3v = ws[(k4 + 3) * D3 + col];
            float4 r0 = *reinterpret_cast<const float4*>(&rows[(nb + 0) * D2 + k4]);
            float4 r1 = *reinterpret_cast<const float4*>(&rows[(nb + 1) * D2 + k4]);
            float4 r2 = *reinterpret_cast<const float4*>(&rows[(nb + 2) * D2 + k4]);
            float4 r3 = *reinterpret_cast<const float4*>(&rows[(nb + 3) * D2 + k4]);
            a0 = fmaf(r0.x, w0, a0); a0 = fmaf(r0.y, w1v, a0);
            a0 = fmaf(r0.z, w2v, a0); a0 = fmaf(r0.w, w3v, a0);
            a1 = fmaf(r1.x, w0, a1); a1 = fmaf(r1.y, w1v, a1);
            a1 = fmaf(r1.z, w2v, a1); a1 = fmaf(r1.w, w3v, a1);
            a2 = fmaf(r2.x, w0, a2); a2 = fmaf(r2.y, w1v, a2);
            a2 = fmaf(r2.z, w2v, a2); a2 = fmaf(r2.w, w3v, a2);
            a3 = fmaf(r3.x, w0, a3); a3 = fmaf(r3.y, w1v, a3);
            a3 = fmaf(r3.z, w2v, a3); a3 = fmaf(r3.w, w3v, a3);
        }
        if (nb + 0 < cnt) runmax = fmaxf(runmax, a0);
        if (nb + 1 < cnt) runmax = fmaxf(runmax, a1);
        if (nb + 2 < cnt) runmax = fmaxf(runmax, a2);
        if (nb + 3 < cnt) runmax = fmaxf(runmax, a3);
    }
    red[tid] = runmax;
    __syncthreads();
    if (tid < 128) {
        float v = fmaxf(fmaxf(red[tid], red[tid + 128]),
                        fmaxf(red[tid + 256], red[tid + 384]));
        g[(size_t)gi * D3 + tid] = v;
    }
}

// ---- fused MLP head: z1 -> z2 -> out, all intermediates in LDS -------------
// 512 thr, 4 graphs per block. fc1: col t x 4 graphs; fc2: col t&255 x 2
// graphs; out: 128 threads per graph, shuffle+LDS reduce.
__global__ __launch_bounds__(512) void k_mlp(const float* __restrict__ g,
                                             const float* __restrict__ fc1_w,
                                             const float* __restrict__ fc1_b,
                                             const float* __restrict__ fc2_w,
                                             const float* __restrict__ fc2_b,
                                             const float* __restrict__ out_w,
                                             const float* __restrict__ out_b,
                                             float* __restrict__ out) {
    __shared__ float gs[4 * D3];     // 2 KB
    __shared__ float zs[4 * H1SZ];   // 8 KB
    __shared__ float z2s[4 * H2SZ];  // 4 KB
    __shared__ float red[8];
    int t = threadIdx.x;
    int g0 = blockIdx.x * 4;
    if (t < 4 * D3) gs[t] = g[(size_t)g0 * D3 + t];
    __syncthreads();
    // fc1
    {
        float bias = fc1_b[t];
        float a0 = bias, a1 = bias, a2 = bias, a3 = bias;
        for (int k = 0; k < D3; ++k) {
            float wv = fc1_w[k * H1SZ + t];
            a0 = fmaf(gs[k], wv, a0);
            a1 = fmaf(gs[D3 + k], wv, a1);
            a2 = fmaf(gs[2 * D3 + k], wv, a2);
            a3 = fmaf(gs[3 * D3 + k], wv, a3);
        }
        zs[0 * H1SZ + t] = fmaxf(a0, 0.f);
        zs[1 * H1SZ + t] = fmaxf(a1, 0.f);
        zs[2 * H1SZ + t] = fmaxf(a2, 0.f);
        zs[3 * H1SZ + t] = fmaxf(a3, 0.f);
    }
    __syncthreads();
    // fc2: thread t -> col t&255, graphs {2*(t>>8), 2*(t>>8)+1}
    {
        int ct = t & 255, jp = t >> 8;
        float bias = fc2_b[ct];
        float a0 = bias, a1 = bias;
        const float* zA = &zs[(2 * jp) * H1SZ];
        const float* zB = &zs[(2 * jp + 1) * H1SZ];
        for (int k = 0; k < H1SZ; ++k) {
            float wv = fc2_w[k * H2SZ + ct];
            a0 = fmaf(zA[k], wv, a0);
            a1 = fmaf(zB[k], wv, a1);
        }
        z2s[(2 * jp) * H2SZ + ct] = fmaxf(a0, 0.f);
        z2s[(2 * jp + 1) * H2SZ + ct] = fmaxf(a1, 0.f);
    }
    __syncthreads();
    // out: graph j = t>>7, col c2 = t&127 (2 cols per thread)
    {
        int j = t >> 7, c2 = t & 127;
        float p = z2s[j * H2SZ + c2] * out_w[c2]
                + z2s[j * H2SZ + c2 + 128] * out_w[c2 + 128];
        #pragma unroll
        for (int off = 32; off; off >>= 1) p += __shfl_down(p, off);
        int lane = t & 63, w8 = t >> 6;
        if (lane == 0) red[w8] = p;
        __syncthreads();
        if (t < 4) out[g0 + t] = red[2 * t] + red[2 * t + 1] + out_b[0];
    }
}

extern "C" void kernel_launch(void* const* d_in, const int* in_sizes, int n_in,
                              void* d_out, int out_size, void* d_ws, size_t ws_size,
                              hipStream_t stream) {
    const float* x        = (const float*)d_in[0];
    const int*   ei       = (const int*)d_in[1];
    // d_in[2] = edge_intra (unused by reference)
    const int*   batch    = (const int*)d_in[3];
    // d_in[4] = num_graphs scalar (== out_size)
    const float* w1       = (const float*)d_in[5];
    const float* b1       = (const float*)d_in[6];
    const float* w2       = (const float*)d_in[7];
    const float* b2       = (const float*)d_in[8];
    const float* gat_w    = (const float*)d_in[9];
    const float* att_src  = (const float*)d_in[10];
    const float* att_dst  = (const float*)d_in[11];
    const float* gat_b    = (const float*)d_in[12];
    const float* gcn_w    = (const float*)d_in[13];
    const float* gcn_b    = (const float*)d_in[14];
    const float* fc1_w    = (const float*)d_in[15];
    const float* fc1_b    = (const float*)d_in[16];
    const float* fc2_w    = (const float*)d_in[17];
    const float* fc2_b    = (const float*)d_in[18];
    const float* out_w    = (const float*)d_in[19];
    const float* out_b    = (const float*)d_in[20];
    float* out = (float*)d_out;

    const int N = in_sizes[0] / F_IN;
    const int E = in_sizes[1] / 2;
    const int M = E + N;             // edges incl. self-loops
    const int G = out_size;
    const int NBUK = (N + BUKSZ - 1) / BUKSZ;
    const int embB   = N / 32;
    const int partB  = (E + PART_CH - 1) / PART_CH;
    const int boundB = (N + 255) / 256;

    // workspace carve-up
    char* p = (char*)d_ws;
    size_t off = 0;
    auto alloc = [&](size_t bytes) { void* q = p + off; off += (bytes + 255) & ~(size_t)255; return q; };
    int2*  tmp     = (int2*)alloc((size_t)NBUK * CAP * 8);   // 16 MB
    int*   csr_src = (int*)alloc((size_t)M * 4);
    float* hp      = (float*)alloc((size_t)N * D2 * 4);      // row-major [N][64]
    float* hscaled = (float*)alloc((size_t)N * D2 * 4);      // row-major [N][64]
    float* hagg    = (float*)alloc((size_t)N * D2 * 4);      // row-major [N][64]
    int*   offs    = (int*)alloc((size_t)N * 4);
    int*   degi    = (int*)alloc((size_t)N * 4);
    float* dinv    = (float*)alloc((size_t)N * 4);
    float* a_s     = (float*)alloc((size_t)N * 4);
    float* a_d     = (float*)alloc((size_t)N * 4);
    int*   gcount  = (int*)alloc((size_t)NBUK * 4);
    int*   gstart  = (int*)alloc((size_t)(G + 1) * 4);
    float* g       = (float*)alloc((size_t)G * D3 * 4);
    float* v_src   = (float*)alloc(D2 * 4);
    float* v_dst   = (float*)alloc(D2 * 4);

    hipMemsetAsync(gcount, 0, (size_t)NBUK * 4, stream);

    k_vecproj<<<1, 64, 0, stream>>>(gat_w, att_src, att_dst, v_src, v_dst);
    // fused: node embedding | edge partition | graph bounds
    k_fused<<<embB + partB + boundB, 256, 0, stream>>>(
        x, w1, b1, w2, b2, gat_w, v_src, v_dst, hp, a_s, a_d,
        ei, gcount, tmp, batch, gstart, N, E, NBUK, G, embB, partB);
    // CSR finalize (inline prefix over gcount)
    k_build<<<NBUK, 256, 0, stream>>>(tmp, gcount, offs, degi, dinv, csr_src, N);
    // pull-mode aggregations (no atomics, 16-deep predicated pipelines)
    k_gat<<<(N + 3) / 4, 256, 0, stream>>>(csr_src, offs, degi, a_s, a_d, hp,
                                           gat_b, dinv, hscaled, N);
    k_gcn<<<(N + 3) / 4, 256, 0, stream>>>(csr_src, offs, degi, dinv, hscaled, hagg, N);
    // per-graph GEMM + relu + max-pool (LDS-tiled)
    k_pool<<<G, 512, 0, stream>>>(hagg, gcn_w, gcn_b, gstart, g);
    // fused MLP head (fc1 -> fc2 -> out in one kernel)
    k_mlp<<<G / 4, 512, 0, stream>>>(g, fc1_w, fc1_b, fc2_w, fc2_b, out_w, out_b, out);
}

// Round 14
// 346.078 us; speedup vs baseline: 1.0703x; 1.0703x over previous
//
#include <hip/hip_runtime.h>
#include <hip/hip_bf16.h>

// ---------------------------------------------------------------------------
// Sizes (fixed for this problem): N=100000 (mult of 32), E=1600000, G=512
#define F_IN 53
#define D1   128
#define D2   64
#define D3   128   // 2*D2
#define H1SZ 512
#define H2SZ 256

#define BUKSZ   256          // nodes per bucket (bucket = dst >> 8)
#define BUKMAX  512          // max buckets supported (N <= 131072)
#define CAP     5120         // tmp capacity per bucket (avg fill ~4100)
#define PART_CH 4096         // edges per part block (16 per thread)

// v_src[k] = sum_c gat_w[k][c] * att_src[c]  (and same for dst)
__global__ void k_vecproj(const float* __restrict__ gat_w,
                          const float* __restrict__ att_src,
                          const float* __restrict__ att_dst,
                          float* __restrict__ v_src, float* __restrict__ v_dst) {
    int k = threadIdx.x;  // 0..63
    float as = 0.f, ad = 0.f;
    #pragma unroll
    for (int c = 0; c < D2; ++c) {
        float w = gat_w[k * D2 + c];
        as = fmaf(w, att_src[c], as);
        ad = fmaf(w, att_dst[c], ad);
    }
    v_src[k] = as;
    v_dst[k] = ad;
}

// ---- fused: node embedding | edge bucket partition | graph bounds ----------
// LDS overlay: buf[32][64] serves as xs (cols<53) during dense1, then h2s.
// Safe: each buf row is read only by its owner wave, and the owner's reads
// complete (program order) before its h2 writes. LDS 24.2 KB -> 6 blocks/CU.
__global__ __launch_bounds__(256) void k_fused(const float* __restrict__ x,
                                               const float* __restrict__ w1,
                                               const float* __restrict__ b1,
                                               const float* __restrict__ w2,
                                               const float* __restrict__ b2,
                                               const float* __restrict__ gat_w,
                                               const float* __restrict__ v_src,
                                               const float* __restrict__ v_dst,
                                               float* __restrict__ hp,
                                               float* __restrict__ a_s,
                                               float* __restrict__ a_d,
                                               const int* __restrict__ ei,
                                               int* __restrict__ gcount,
                                               int2* __restrict__ tmp,
                                               const int* __restrict__ batch,
                                               int* __restrict__ gstart,
                                               int N, int E, int NBUK, int G,
                                               int embB, int partB) {
    __shared__ __align__(16) union {
        struct { float buf[32][64]; float h1s[32][D1]; } e;  // 8 + 16 KB
        int hist[BUKMAX];
    } sm;
    int tid = threadIdx.x;
    int bid = blockIdx.x;

    if (bid >= embB) {
        if (bid < embB + partB) {
            // ---------------- edge bucket partition ----------------
            for (int i = tid; i < NBUK; i += 256) sm.hist[i] = 0;
            __syncthreads();
            int k0 = (bid - embB) * PART_CH;
            int ss[16], dd[16];
            #pragma unroll
            for (int i = 0; i < 16; ++i) {
                int k = k0 + i * 256 + tid;
                if (k < E) {
                    ss[i] = ei[k];
                    dd[i] = ei[E + k];
                    atomicAdd(&sm.hist[dd[i] >> 8], 1);
                } else {
                    dd[i] = -1;
                }
            }
            __syncthreads();
            for (int b = tid; b < NBUK; b += 256) {
                int c = sm.hist[b];
                if (c > 0) sm.hist[b] = b * CAP + atomicAdd(&gcount[b], c);
            }
            __syncthreads();
            #pragma unroll
            for (int i = 0; i < 16; ++i) {
                if (dd[i] >= 0) {
                    int b = dd[i] >> 8;
                    int pos = atomicAdd(&sm.hist[b], 1);
                    if (pos < (b + 1) * CAP) tmp[pos] = make_int2(ss[i], dd[i]);
                }
            }
        } else {
            // ---------------- graph bounds (batch sorted) ----------------
            int n = (bid - embB - partB) * 256 + tid;
            if (n < N) {
                int b = batch[n];
                if (n == 0) {
                    for (int g = 0; g <= b; ++g) gstart[g] = 0;
                } else {
                    int pb = batch[n - 1];
                    for (int g = pb + 1; g <= b; ++g) gstart[g] = n;
                }
                if (n == N - 1) {
                    for (int g = b + 1; g <= G; ++g) gstart[g] = N;
                }
            }
        }
        return;
    }

    // ---------------- fused node embedding ----------------
    int n0 = bid * 32;                // N divisible by 32
    for (int i = tid; i < 32 * F_IN; i += 256) {
        int node = i / F_IN, kk = i - node * F_IN;
        sm.e.buf[node][kk] = x[(size_t)n0 * F_IN + i];
    }
    __syncthreads();   // the ONLY barrier: everything below is wave-local
    int c = tid & 63, grp = tid >> 6;
    int nb = grp * 8;                 // this wave's 8 nodes
    // dense1: h1 = relu(x@w1+b1); cols (c, c+64) x 8 nodes
    {
        float acc0[8], acc1[8];
        float bb0 = b1[c], bb1 = b1[c + 64];
        #pragma unroll
        for (int j = 0; j < 8; ++j) { acc0[j] = bb0; acc1[j] = bb1; }
        #pragma unroll 1
        for (int kc = 0; kc < 13; ++kc) {        // k = 0..51 in float4 chunks
            int k4 = kc * 4;
            float wa0 = w1[(k4 + 0) * D1 + c];
            float wa1 = w1[(k4 + 1) * D1 + c];
            float wa2 = w1[(k4 + 2) * D1 + c];
            float wa3 = w1[(k4 + 3) * D1 + c];
            float wb0 = w1[(k4 + 0) * D1 + c + 64];
            float wb1 = w1[(k4 + 1) * D1 + c + 64];
            float wb2 = w1[(k4 + 2) * D1 + c + 64];
            float wb3 = w1[(k4 + 3) * D1 + c + 64];
            #pragma unroll
            for (int j = 0; j < 8; ++j) {
                float4 xv = *reinterpret_cast<const float4*>(&sm.e.buf[nb + j][k4]);
                acc0[j] = fmaf(xv.x, wa0, acc0[j]);
                acc0[j] = fmaf(xv.y, wa1, acc0[j]);
                acc0[j] = fmaf(xv.z, wa2, acc0[j]);
                acc0[j] = fmaf(xv.w, wa3, acc0[j]);
                acc1[j] = fmaf(xv.x, wb0, acc1[j]);
                acc1[j] = fmaf(xv.y, wb1, acc1[j]);
                acc1[j] = fmaf(xv.z, wb2, acc1[j]);
                acc1[j] = fmaf(xv.w, wb3, acc1[j]);
            }
        }
        {   // k = 52 remainder
            float wa = w1[52 * D1 + c], wb = w1[52 * D1 + c + 64];
            #pragma unroll
            for (int j = 0; j < 8; ++j) {
                float xv = sm.e.buf[nb + j][52];
                acc0[j] = fmaf(xv, wa, acc0[j]);
                acc1[j] = fmaf(xv, wb, acc1[j]);
            }
        }
        #pragma unroll
        for (int j = 0; j < 8; ++j) {
            sm.e.h1s[nb + j][c]      = fmaxf(acc0[j], 0.f);
            sm.e.h1s[nb + j][c + 64] = fmaxf(acc1[j], 0.f);
        }
    }
    // dense2: h2 = relu(h1@w2+b2); col c x 8 nodes, K=128 (wave-local rows)
    float h2v[8];
    {
        float bb = b2[c];
        #pragma unroll
        for (int j = 0; j < 8; ++j) h2v[j] = bb;
        #pragma unroll 1
        for (int kc = 0; kc < 32; ++kc) {
            int k4 = kc * 4;
            float w0 = w2[(k4 + 0) * D2 + c];
            float w1v = w2[(k4 + 1) * D2 + c];
            float w2v = w2[(k4 + 2) * D2 + c];
            float w3v = w2[(k4 + 3) * D2 + c];
            #pragma unroll
            for (int j = 0; j < 8; ++j) {
                float4 hv = *reinterpret_cast<const float4*>(&sm.e.h1s[nb + j][k4]);
                h2v[j] = fmaf(hv.x, w0, h2v[j]);
                h2v[j] = fmaf(hv.y, w1v, h2v[j]);
                h2v[j] = fmaf(hv.z, w2v, h2v[j]);
                h2v[j] = fmaf(hv.w, w3v, h2v[j]);
            }
        }
        // overwrite own wave's buf rows with h2 (xs reads done in program order)
        #pragma unroll
        for (int j = 0; j < 8; ++j) {
            float v = fmaxf(h2v[j], 0.f);
            h2v[j] = v;
            sm.e.buf[nb + j][c] = v;
        }
    }
    // a_s = h2 . v_src ; a_d = h2 . v_dst  (wave shuffle reduce; lane == c)
    {
        float vs = v_src[c], vd = v_dst[c];
        #pragma unroll
        for (int j = 0; j < 8; ++j) {
            float ps = h2v[j] * vs, pd = h2v[j] * vd;
            #pragma unroll
            for (int off = 32; off; off >>= 1) {
                ps += __shfl_down(ps, off);
                pd += __shfl_down(pd, off);
            }
            if (c == 0) { int n = n0 + nb + j; a_s[n] = ps; a_d[n] = pd; }
        }
    }
    // hp = h2 @ gat_w; col c x 8 nodes, K=64 (wave-local buf rows)
    {
        float acc[8];
        #pragma unroll
        for (int j = 0; j < 8; ++j) acc[j] = 0.f;
        #pragma unroll 1
        for (int kc = 0; kc < 16; ++kc) {
            int k4 = kc * 4;
            float w0 = gat_w[(k4 + 0) * D2 + c];
            float w1v = gat_w[(k4 + 1) * D2 + c];
            float w2v = gat_w[(k4 + 2) * D2 + c];
            float w3v = gat_w[(k4 + 3) * D2 + c];
            #pragma unroll
            for (int j = 0; j < 8; ++j) {
                float4 hv = *reinterpret_cast<const float4*>(&sm.e.buf[nb + j][k4]);
                acc[j] = fmaf(hv.x, w0, acc[j]);
                acc[j] = fmaf(hv.y, w1v, acc[j]);
                acc[j] = fmaf(hv.z, w2v, acc[j]);
                acc[j] = fmaf(hv.w, w3v, acc[j]);
            }
        }
        #pragma unroll
        for (int j = 0; j < 8; ++j)
            hp[(size_t)(n0 + nb + j) * D2 + c] = acc[j];
    }
}

// ---- CSR build: one block per bucket; inline prefix over gcount ------------
__global__ __launch_bounds__(256) void k_build(const int2* __restrict__ tmp,
                                               const int* __restrict__ gcount,
                                               int* __restrict__ offs,
                                               int* __restrict__ degi,
                                               float* __restrict__ dinv,
                                               int* __restrict__ csr_src, int N) {
    __shared__ int ldeg[256];
    __shared__ int lsc[256];
    __shared__ int lcur[256];
    __shared__ int pref[256];
    int tid = threadIdx.x;
    int b = blockIdx.x;
    int n0 = b * BUKSZ;
    int nvalid = min(BUKSZ, N - n0);
    int cnt = min(gcount[b], CAP);
    // inline exclusive prefix: sum_{i<b} min(gcount[i],CAP)  (b <= 512)
    int acc = 0;
    for (int i = tid; i < b; i += 256) acc += min(gcount[i], CAP);
    pref[tid] = acc;
    ldeg[tid] = 0;
    __syncthreads();
    #pragma unroll
    for (int off = 128; off; off >>= 1) {
        if (tid < off) pref[tid] += pref[tid + off];
        __syncthreads();
    }
    int base = pref[0] + n0;   // edges before + self-loops before
    for (int i = tid; i < cnt; i += 256) {
        int2 e = tmp[b * CAP + i];
        atomicAdd(&ldeg[e.y & 255], 1);
    }
    __syncthreads();
    int d = (tid < nvalid) ? (ldeg[tid] + 1) : 0;   // +1 self-loop
    lsc[tid] = d;
    __syncthreads();
    #pragma unroll
    for (int off = 1; off < 256; off <<= 1) {
        int u = (tid >= off) ? lsc[tid - off] : 0;
        __syncthreads();
        lsc[tid] += u;
        __syncthreads();
    }
    int excl = lsc[tid] - d;
    if (tid < nvalid) {
        int n = n0 + tid;
        offs[n] = base + excl;
        degi[n] = d;
        dinv[n] = rsqrtf((float)d);
        lcur[tid] = excl;
    }
    __syncthreads();
    for (int i = tid; i < cnt; i += 256) {
        int2 e = tmp[b * CAP + i];
        int nl = e.y & 255;
        int r = atomicAdd(&lcur[nl], 1);
        csr_src[base + r] = e.x;
    }
    __syncthreads();
    if (tid < nvalid) {
        int r = atomicAdd(&lcur[tid], 1);
        csr_src[base + r] = n0 + tid;   // self-loop
    }
}

// ---- GAT pull: softmax in regs; alpha AND src indices cached in LDS --------
// hscaled[n] = dinv[n] * relu(sum alpha*hp[src] + gat_b)
__global__ __launch_bounds__(256) void k_gat(const int* __restrict__ csr_src,
                                             const int* __restrict__ offs,
                                             const int* __restrict__ degi,
                                             const float* __restrict__ a_s,
                                             const float* __restrict__ a_d,
                                             const float* __restrict__ hp,
                                             const float* __restrict__ gat_b,
                                             const float* __restrict__ dinv,
                                             float* __restrict__ hscaled, int N) {
    __shared__ float ac[4][128];
    __shared__ int   si[4][128];
    int wv = threadIdx.x >> 6, lane = threadIdx.x & 63;
    int node = blockIdx.x * 4 + wv;
    if (node >= N) return;   // N%4==0 -> never taken; no barriers below
    int start = offs[node], deg = degi[node];
    int dcap = min(deg, 128);
    float adn = a_d[node];
    // phase A: lane-parallel online softmax stats; stash raw e + src in LDS
    float m = -1e30f, ssum = 0.f;
    for (int p = lane; p < deg; p += 64) {
        int s = csr_src[start + p];
        float e = a_s[s] + adn;
        e = (e > 0.f) ? e : 0.2f * e;
        if (p < 128) { ac[wv][p] = e; si[wv][p] = s; }
        float mn = fmaxf(m, e);
        ssum = ssum * __expf(m - mn) + __expf(e - mn);
        m = mn;
    }
    #pragma unroll
    for (int off = 32; off; off >>= 1) {
        float om = __shfl_xor(m, off);
        float os = __shfl_xor(ssum, off);
        float mn = fmaxf(m, om);
        ssum = ssum * __expf(m - mn) + os * __expf(om - mn);
        m = mn;
    }
    float rinv = 1.0f / ssum;
    // convert stashed e -> alpha (same lane wrote p=lane and p=lane+64)
    if (lane < dcap)      ac[wv][lane]      = __expf(ac[wv][lane] - m) * rinv;
    if (lane + 64 < dcap) ac[wv][lane + 64] = __expf(ac[wv][lane + 64] - m) * rinv;
    // phase B: 16-deep fully-predicated weighted gather, indices from LDS
    float acc = 0.f;
    for (int pp = 0; pp < dcap; pp += 16) {
        int s[16]; float w[16];
        #pragma unroll
        for (int i = 0; i < 16; ++i) {
            int q = pp + i;
            int qc = (q < dcap) ? q : (dcap - 1);
            s[i] = si[wv][qc];
            w[i] = (q < dcap) ? ac[wv][q] : 0.f;
        }
        float v[16];
        #pragma unroll
        for (int i = 0; i < 16; ++i) v[i] = hp[(size_t)s[i] * D2 + lane];
        #pragma unroll
        for (int i = 0; i < 16; ++i) acc = fmaf(w[i], v[i], acc);
    }
    for (int p = 128; p < deg; ++p) {   // deg > 128 overflow (essentially never)
        int s = csr_src[start + p];
        float e = a_s[s] + adn;
        e = (e > 0.f) ? e : 0.2f * e;
        acc = fmaf(__expf(e - m) * rinv, hp[(size_t)s * D2 + lane], acc);
    }
    hscaled[(size_t)node * D2 + lane] = dinv[node] * fmaxf(acc + gat_b[lane], 0.f);
}

// ---- GCN pull: hagg[n] = dinv[n]*sum hscaled[src]; 16-deep predicated ------
__global__ __launch_bounds__(256) void k_gcn(const int* __restrict__ csr_src,
                                             const int* __restrict__ offs,
                                             const int* __restrict__ degi,
                                             const float* __restrict__ dinv,
                                             const float* __restrict__ hscaled,
                                             float* __restrict__ hagg, int N) {
    int node = blockIdx.x * 4 + (threadIdx.x >> 6);
    int lane = threadIdx.x & 63;
    if (node >= N) return;
    int start = offs[node], deg = degi[node];
    float acc = 0.f;
    for (int pp = 0; pp < deg; pp += 16) {
        int s[16];
        #pragma unroll
        for (int i = 0; i < 16; ++i) {
            int q = pp + i;
            int qc = (q < deg) ? q : (deg - 1);
            s[i] = csr_src[start + qc];
        }
        float v[16];
        #pragma unroll
        for (int i = 0; i < 16; ++i) v[i] = hscaled[(size_t)s[i] * D2 + lane];
        #pragma unroll
        for (int i = 0; i < 16; ++i) acc += (pp + i < deg) ? v[i] : 0.f;
    }
    hagg[(size_t)node * D2 + lane] = acc * dinv[node];
}

// per-graph fused GEMM [*,64]@[64,128]+bias+relu + max-pool
// 512 thr: LDS-staged 16-node chunks, col=tid&127, 4 nodes/thread, float4 K
__global__ __launch_bounds__(512) void k_pool(const float* __restrict__ hagg,
                                              const float* __restrict__ gcn_w,
                                              const float* __restrict__ gcn_b,
                                              const int* __restrict__ gstart,
                                              float* __restrict__ g) {
    __shared__ float ws[D2 * D3];                 // 32 KB
    __shared__ __align__(16) float rows[16 * D2]; // 4 KB
    __shared__ float red[512];
    int tid = threadIdx.x;
    int gi = blockIdx.x;
    for (int i = tid; i < D2 * D3; i += 512) ws[i] = gcn_w[i];
    int ns = gstart[gi], ne = gstart[gi + 1];
    int col = tid & 127, grp = tid >> 7;   // 4 groups x 4 nodes
    float bias = gcn_b[col];
    float runmax = 0.f;   // relu floor; also handles empty graphs
    for (int base = ns; base < ne; base += 16) {
        int cnt = min(16, ne - base);
        __syncthreads();   // rows reuse + (first iter) ws ready
        for (int i = tid; i < cnt * D2; i += 512)
            rows[i] = hagg[(size_t)base * D2 + i];
        __syncthreads();
        int nb = grp * 4;
        float a0 = bias, a1 = bias, a2 = bias, a3 = bias;
        #pragma unroll 4
        for (int kc = 0; kc < 16; ++kc) {
            int k4 = kc * 4;
            float w0 = ws[(k4 + 0) * D3 + col];
            float w1v = ws[(k4 + 1) * D3 + col];
            float w2v = ws[(k4 + 2) * D3 + col];
            float w3v = ws[(k4 + 3) * D3 + col];
            float4 r0 = *reinterpret_cast<const float4*>(&rows[(nb + 0) * D2 + k4]);
            float4 r1 = *reinterpret_cast<const float4*>(&rows[(nb + 1) * D2 + k4]);
            float4 r2 = *reinterpret_cast<const float4*>(&rows[(nb + 2) * D2 + k4]);
            float4 r3 = *reinterpret_cast<const float4*>(&rows[(nb + 3) * D2 + k4]);
            a0 = fmaf(r0.x, w0, a0); a0 = fmaf(r0.y, w1v, a0);
            a0 = fmaf(r0.z, w2v, a0); a0 = fmaf(r0.w, w3v, a0);
            a1 = fmaf(r1.x, w0, a1); a1 = fmaf(r1.y, w1v, a1);
            a1 = fmaf(r1.z, w2v, a1); a1 = fmaf(r1.w, w3v, a1);
            a2 = fmaf(r2.x, w0, a2); a2 = fmaf(r2.y, w1v, a2);
            a2 = fmaf(r2.z, w2v, a2); a2 = fmaf(r2.w, w3v, a2);
            a3 = fmaf(r3.x, w0, a3); a3 = fmaf(r3.y, w1v, a3);
            a3 = fmaf(r3.z, w2v, a3); a3 = fmaf(r3.w, w3v, a3);
        }
        if (nb + 0 < cnt) runmax = fmaxf(runmax, a0);
        if (nb + 1 < cnt) runmax = fmaxf(runmax, a1);
        if (nb + 2 < cnt) runmax = fmaxf(runmax, a2);
        if (nb + 3 < cnt) runmax = fmaxf(runmax, a3);
    }
    red[tid] = runmax;
    __syncthreads();
    if (tid < 128) {
        float v = fmaxf(fmaxf(red[tid], red[tid + 128]),
                        fmaxf(red[tid + 256], red[tid + 384]));
        g[(size_t)gi * D3 + tid] = v;
    }
}

// ---- fused MLP head: z1 -> z2 -> out, all intermediates in LDS -------------
// 512 thr, 4 graphs per block. fc1: col t x 4 graphs; fc2: col t&255 x 2
// graphs; out: 128 threads per graph, shuffle+LDS reduce.
__global__ __launch_bounds__(512) void k_mlp(const float* __restrict__ g,
                                             const float* __restrict__ fc1_w,
                                             const float* __restrict__ fc1_b,
                                             const float* __restrict__ fc2_w,
                                             const float* __restrict__ fc2_b,
                                             const float* __restrict__ out_w,
                                             const float* __restrict__ out_b,
                                             float* __restrict__ out) {
    __shared__ float gs[4 * D3];     // 2 KB
    __shared__ float zs[4 * H1SZ];   // 8 KB
    __shared__ float z2s[4 * H2SZ];  // 4 KB
    __shared__ float red[8];
    int t = threadIdx.x;
    int g0 = blockIdx.x * 4;
    if (t < 4 * D3) gs[t] = g[(size_t)g0 * D3 + t];
    __syncthreads();
    // fc1
    {
        float bias = fc1_b[t];
        float a0 = bias, a1 = bias, a2 = bias, a3 = bias;
        for (int k = 0; k < D3; ++k) {
            float wv = fc1_w[k * H1SZ + t];
            a0 = fmaf(gs[k], wv, a0);
            a1 = fmaf(gs[D3 + k], wv, a1);
            a2 = fmaf(gs[2 * D3 + k], wv, a2);
            a3 = fmaf(gs[3 * D3 + k], wv, a3);
        }
        zs[0 * H1SZ + t] = fmaxf(a0, 0.f);
        zs[1 * H1SZ + t] = fmaxf(a1, 0.f);
        zs[2 * H1SZ + t] = fmaxf(a2, 0.f);
        zs[3 * H1SZ + t] = fmaxf(a3, 0.f);
    }
    __syncthreads();
    // fc2: thread t -> col t&255, graphs {2*(t>>8), 2*(t>>8)+1}
    {
        int ct = t & 255, jp = t >> 8;
        float bias = fc2_b[ct];
        float a0 = bias, a1 = bias;
        const float* zA = &zs[(2 * jp) * H1SZ];
        const float* zB = &zs[(2 * jp + 1) * H1SZ];
        for (int k = 0; k < H1SZ; ++k) {
            float wv = fc2_w[k * H2SZ + ct];
            a0 = fmaf(zA[k], wv, a0);
            a1 = fmaf(zB[k], wv, a1);
        }
        z2s[(2 * jp) * H2SZ + ct] = fmaxf(a0, 0.f);
        z2s[(2 * jp + 1) * H2SZ + ct] = fmaxf(a1, 0.f);
    }
    __syncthreads();
    // out: graph j = t>>7, col c2 = t&127 (2 cols per thread)
    {
        int j = t >> 7, c2 = t & 127;
        float p = z2s[j * H2SZ + c2] * out_w[c2]
                + z2s[j * H2SZ + c2 + 128] * out_w[c2 + 128];
        #pragma unroll
        for (int off = 32; off; off >>= 1) p += __shfl_down(p, off);
        int lane = t & 63, w8 = t >> 6;
        if (lane == 0) red[w8] = p;
        __syncthreads();
        if (t < 4) out[g0 + t] = red[2 * t] + red[2 * t + 1] + out_b[0];
    }
}

extern "C" void kernel_launch(void* const* d_in, const int* in_sizes, int n_in,
                              void* d_out, int out_size, void* d_ws, size_t ws_size,
                              hipStream_t stream) {
    const float* x        = (const float*)d_in[0];
    const int*   ei       = (const int*)d_in[1];
    // d_in[2] = edge_intra (unused by reference)
    const int*   batch    = (const int*)d_in[3];
    // d_in[4] = num_graphs scalar (== out_size)
    const float* w1       = (const float*)d_in[5];
    const float* b1       = (const float*)d_in[6];
    const float* w2       = (const float*)d_in[7];
    const float* b2       = (const float*)d_in[8];
    const float* gat_w    = (const float*)d_in[9];
    const float* att_src  = (const float*)d_in[10];
    const float* att_dst  = (const float*)d_in[11];
    const float* gat_b    = (const float*)d_in[12];
    const float* gcn_w    = (const float*)d_in[13];
    const float* gcn_b    = (const float*)d_in[14];
    const float* fc1_w    = (const float*)d_in[15];
    const float* fc1_b    = (const float*)d_in[16];
    const float* fc2_w    = (const float*)d_in[17];
    const float* fc2_b    = (const float*)d_in[18];
    const float* out_w    = (const float*)d_in[19];
    const float* out_b    = (const float*)d_in[20];
    float* out = (float*)d_out;

    const int N = in_sizes[0] / F_IN;
    const int E = in_sizes[1] / 2;
    const int M = E + N;             // edges incl. self-loops
    const int G = out_size;
    const int NBUK = (N + BUKSZ - 1) / BUKSZ;
    const int embB   = N / 32;
    const int partB  = (E + PART_CH - 1) / PART_CH;
    const int boundB = (N + 255) / 256;

    // workspace carve-up
    char* p = (char*)d_ws;
    size_t off = 0;
    auto alloc = [&](size_t bytes) { void* q = p + off; off += (bytes + 255) & ~(size_t)255; return q; };
    int2*  tmp     = (int2*)alloc((size_t)NBUK * CAP * 8);   // 16 MB
    int*   csr_src = (int*)alloc((size_t)M * 4);
    float* hp      = (float*)alloc((size_t)N * D2 * 4);      // row-major [N][64]
    float* hscaled = (float*)alloc((size_t)N * D2 * 4);      // row-major [N][64]
    float* hagg    = (float*)alloc((size_t)N * D2 * 4);      // row-major [N][64]
    int*   offs    = (int*)alloc((size_t)N * 4);
    int*   degi    = (int*)alloc((size_t)N * 4);
    float* dinv    = (float*)alloc((size_t)N * 4);
    float* a_s     = (float*)alloc((size_t)N * 4);
    float* a_d     = (float*)alloc((size_t)N * 4);
    int*   gcount  = (int*)alloc((size_t)NBUK * 4);
    int*   gstart  = (int*)alloc((size_t)(G + 1) * 4);
    float* g       = (float*)alloc((size_t)G * D3 * 4);
    float* v_src   = (float*)alloc(D2 * 4);
    float* v_dst   = (float*)alloc(D2 * 4);

    hipMemsetAsync(gcount, 0, (size_t)NBUK * 4, stream);

    k_vecproj<<<1, 64, 0, stream>>>(gat_w, att_src, att_dst, v_src, v_dst);
    // fused: node embedding | edge partition | graph bounds
    k_fused<<<embB + partB + boundB, 256, 0, stream>>>(
        x, w1, b1, w2, b2, gat_w, v_src, v_dst, hp, a_s, a_d,
        ei, gcount, tmp, batch, gstart, N, E, NBUK, G, embB, partB);
    // CSR finalize (inline prefix over gcount)
    k_build<<<NBUK, 256, 0, stream>>>(tmp, gcount, offs, degi, dinv, csr_src, N);
    // pull-mode aggregations (no atomics, 16-deep predicated pipelines)
    k_gat<<<(N + 3) / 4, 256, 0, stream>>>(csr_src, offs, degi, a_s, a_d, hp,
                                           gat_b, dinv, hscaled, N);
    k_gcn<<<(N + 3) / 4, 256, 0, stream>>>(csr_src, offs, degi, dinv, hscaled, hagg, N);
    // per-graph GEMM + relu + max-pool (LDS-tiled)
    k_pool<<<G, 512, 0, stream>>>(hagg, gcn_w, gcn_b, gstart, g);
    // fused MLP head (fc1 -> fc2 -> out in one kernel)
    k_mlp<<<G / 4, 512, 0, stream>>>(g, fc1_w, fc1_b, fc2_w, fc2_b, out_w, out_b, out);
}

// Round 15
// 320.927 us; speedup vs baseline: 1.1542x; 1.0784x over previous
//
#include <hip/hip_runtime.h>
#include <hip/hip_bf16.h>

// ---------------------------------------------------------------------------
// Sizes (fixed for this problem): N=100000 (mult of 32), E=1600000, G=512
#define F_IN 53
#define D1   128
#define D2   64
#define D3   128   // 2*D2
#define H1SZ 512
#define H2SZ 256

#define BUKSZ   256          // nodes per bucket (bucket = dst >> 8)
#define BUKMAX  512          // max buckets supported (N <= 131072)
#define CAP     5120         // tmp capacity per bucket (avg fill ~4100)
#define PART_CH 4096         // edges per part block (16 per thread)

// v_src[k] = sum_c gat_w[k][c] * att_src[c]  (and same for dst)
__global__ void k_vecproj(const float* __restrict__ gat_w,
                          const float* __restrict__ att_src,
                          const float* __restrict__ att_dst,
                          float* __restrict__ v_src, float* __restrict__ v_dst) {
    int k = threadIdx.x;  // 0..63
    float as = 0.f, ad = 0.f;
    #pragma unroll
    for (int c = 0; c < D2; ++c) {
        float w = gat_w[k * D2 + c];
        as = fmaf(w, att_src[c], as);
        ad = fmaf(w, att_dst[c], ad);
    }
    v_src[k] = as;
    v_dst[k] = ad;
}

// ---- fused: node embedding | edge bucket partition | graph bounds ----------
// LDS overlay: buf[32][64] serves as xs (cols<53) during dense1, then h2s.
__global__ __launch_bounds__(256) void k_fused(const float* __restrict__ x,
                                               const float* __restrict__ w1,
                                               const float* __restrict__ b1,
                                               const float* __restrict__ w2,
                                               const float* __restrict__ b2,
                                               const float* __restrict__ gat_w,
                                               const float* __restrict__ v_src,
                                               const float* __restrict__ v_dst,
                                               float* __restrict__ hp,
                                               float* __restrict__ a_s,
                                               float* __restrict__ a_d,
                                               const int* __restrict__ ei,
                                               int* __restrict__ gcount,
                                               int2* __restrict__ tmp,
                                               const int* __restrict__ batch,
                                               int* __restrict__ gstart,
                                               int N, int E, int NBUK, int G,
                                               int embB, int partB) {
    __shared__ __align__(16) union {
        struct { float buf[32][64]; float h1s[32][D1]; } e;  // 8 + 16 KB
        int hist[BUKMAX];
    } sm;
    int tid = threadIdx.x;
    int bid = blockIdx.x;

    if (bid >= embB) {
        if (bid < embB + partB) {
            // ---------------- edge bucket partition ----------------
            for (int i = tid; i < NBUK; i += 256) sm.hist[i] = 0;
            __syncthreads();
            int k0 = (bid - embB) * PART_CH;
            int ss[16], dd[16];
            #pragma unroll
            for (int i = 0; i < 16; ++i) {
                int k = k0 + i * 256 + tid;
                if (k < E) {
                    ss[i] = ei[k];
                    dd[i] = ei[E + k];
                    atomicAdd(&sm.hist[dd[i] >> 8], 1);
                } else {
                    dd[i] = -1;
                }
            }
            __syncthreads();
            for (int b = tid; b < NBUK; b += 256) {
                int c = sm.hist[b];
                if (c > 0) sm.hist[b] = b * CAP + atomicAdd(&gcount[b], c);
            }
            __syncthreads();
            #pragma unroll
            for (int i = 0; i < 16; ++i) {
                if (dd[i] >= 0) {
                    int b = dd[i] >> 8;
                    int pos = atomicAdd(&sm.hist[b], 1);
                    if (pos < (b + 1) * CAP) tmp[pos] = make_int2(ss[i], dd[i]);
                }
            }
        } else {
            // ---------------- graph bounds (batch sorted) ----------------
            int n = (bid - embB - partB) * 256 + tid;
            if (n < N) {
                int b = batch[n];
                if (n == 0) {
                    for (int g = 0; g <= b; ++g) gstart[g] = 0;
                } else {
                    int pb = batch[n - 1];
                    for (int g = pb + 1; g <= b; ++g) gstart[g] = n;
                }
                if (n == N - 1) {
                    for (int g = b + 1; g <= G; ++g) gstart[g] = N;
                }
            }
        }
        return;
    }

    // ---------------- fused node embedding ----------------
    int n0 = bid * 32;                // N divisible by 32
    for (int i = tid; i < 32 * F_IN; i += 256) {
        int node = i / F_IN, kk = i - node * F_IN;
        sm.e.buf[node][kk] = x[(size_t)n0 * F_IN + i];
    }
    __syncthreads();   // the ONLY barrier: everything below is wave-local
    int c = tid & 63, grp = tid >> 6;
    int nb = grp * 8;                 // this wave's 8 nodes
    // dense1: h1 = relu(x@w1+b1); cols (c, c+64) x 8 nodes
    {
        float acc0[8], acc1[8];
        float bb0 = b1[c], bb1 = b1[c + 64];
        #pragma unroll
        for (int j = 0; j < 8; ++j) { acc0[j] = bb0; acc1[j] = bb1; }
        #pragma unroll 1
        for (int kc = 0; kc < 13; ++kc) {        // k = 0..51 in float4 chunks
            int k4 = kc * 4;
            float wa0 = w1[(k4 + 0) * D1 + c];
            float wa1 = w1[(k4 + 1) * D1 + c];
            float wa2 = w1[(k4 + 2) * D1 + c];
            float wa3 = w1[(k4 + 3) * D1 + c];
            float wb0 = w1[(k4 + 0) * D1 + c + 64];
            float wb1 = w1[(k4 + 1) * D1 + c + 64];
            float wb2 = w1[(k4 + 2) * D1 + c + 64];
            float wb3 = w1[(k4 + 3) * D1 + c + 64];
            #pragma unroll
            for (int j = 0; j < 8; ++j) {
                float4 xv = *reinterpret_cast<const float4*>(&sm.e.buf[nb + j][k4]);
                acc0[j] = fmaf(xv.x, wa0, acc0[j]);
                acc0[j] = fmaf(xv.y, wa1, acc0[j]);
                acc0[j] = fmaf(xv.z, wa2, acc0[j]);
                acc0[j] = fmaf(xv.w, wa3, acc0[j]);
                acc1[j] = fmaf(xv.x, wb0, acc1[j]);
                acc1[j] = fmaf(xv.y, wb1, acc1[j]);
                acc1[j] = fmaf(xv.z, wb2, acc1[j]);
                acc1[j] = fmaf(xv.w, wb3, acc1[j]);
            }
        }
        {   // k = 52 remainder
            float wa = w1[52 * D1 + c], wb = w1[52 * D1 + c + 64];
            #pragma unroll
            for (int j = 0; j < 8; ++j) {
                float xv = sm.e.buf[nb + j][52];
                acc0[j] = fmaf(xv, wa, acc0[j]);
                acc1[j] = fmaf(xv, wb, acc1[j]);
            }
        }
        #pragma unroll
        for (int j = 0; j < 8; ++j) {
            sm.e.h1s[nb + j][c]      = fmaxf(acc0[j], 0.f);
            sm.e.h1s[nb + j][c + 64] = fmaxf(acc1[j], 0.f);
        }
    }
    // dense2: h2 = relu(h1@w2+b2); col c x 8 nodes, K=128 (wave-local rows)
    float h2v[8];
    {
        float bb = b2[c];
        #pragma unroll
        for (int j = 0; j < 8; ++j) h2v[j] = bb;
        #pragma unroll 1
        for (int kc = 0; kc < 32; ++kc) {
            int k4 = kc * 4;
            float w0 = w2[(k4 + 0) * D2 + c];
            float w1v = w2[(k4 + 1) * D2 + c];
            float w2v = w2[(k4 + 2) * D2 + c];
            float w3v = w2[(k4 + 3) * D2 + c];
            #pragma unroll
            for (int j = 0; j < 8; ++j) {
                float4 hv = *reinterpret_cast<const float4*>(&sm.e.h1s[nb + j][k4]);
                h2v[j] = fmaf(hv.x, w0, h2v[j]);
                h2v[j] = fmaf(hv.y, w1v, h2v[j]);
                h2v[j] = fmaf(hv.z, w2v, h2v[j]);
                h2v[j] = fmaf(hv.w, w3v, h2v[j]);
            }
        }
        // overwrite own wave's buf rows with h2 (xs reads done in program order)
        #pragma unroll
        for (int j = 0; j < 8; ++j) {
            float v = fmaxf(h2v[j], 0.f);
            h2v[j] = v;
            sm.e.buf[nb + j][c] = v;
        }
    }
    // a_s = h2 . v_src ; a_d = h2 . v_dst  (wave shuffle reduce; lane == c)
    {
        float vs = v_src[c], vd = v_dst[c];
        #pragma unroll
        for (int j = 0; j < 8; ++j) {
            float ps = h2v[j] * vs, pd = h2v[j] * vd;
            #pragma unroll
            for (int off = 32; off; off >>= 1) {
                ps += __shfl_down(ps, off);
                pd += __shfl_down(pd, off);
            }
            if (c == 0) { int n = n0 + nb + j; a_s[n] = ps; a_d[n] = pd; }
        }
    }
    // hp = h2 @ gat_w; col c x 8 nodes, K=64 (wave-local buf rows)
    {
        float acc[8];
        #pragma unroll
        for (int j = 0; j < 8; ++j) acc[j] = 0.f;
        #pragma unroll 1
        for (int kc = 0; kc < 16; ++kc) {
            int k4 = kc * 4;
            float w0 = gat_w[(k4 + 0) * D2 + c];
            float w1v = gat_w[(k4 + 1) * D2 + c];
            float w2v = gat_w[(k4 + 2) * D2 + c];
            float w3v = gat_w[(k4 + 3) * D2 + c];
            #pragma unroll
            for (int j = 0; j < 8; ++j) {
                float4 hv = *reinterpret_cast<const float4*>(&sm.e.buf[nb + j][k4]);
                acc[j] = fmaf(hv.x, w0, acc[j]);
                acc[j] = fmaf(hv.y, w1v, acc[j]);
                acc[j] = fmaf(hv.z, w2v, acc[j]);
                acc[j] = fmaf(hv.w, w3v, acc[j]);
            }
        }
        #pragma unroll
        for (int j = 0; j < 8; ++j)
            hp[(size_t)(n0 + nb + j) * D2 + c] = acc[j];
    }
}

// ---- CSR build: one block per bucket; inline prefix over gcount ------------
__global__ __launch_bounds__(256) void k_build(const int2* __restrict__ tmp,
                                               const int* __restrict__ gcount,
                                               int* __restrict__ offs,
                                               int* __restrict__ degi,
                                               float* __restrict__ dinv,
                                               int* __restrict__ csr_src, int N) {
    __shared__ int ldeg[256];
    __shared__ int lsc[256];
    __shared__ int lcur[256];
    __shared__ int pref[256];
    int tid = threadIdx.x;
    int b = blockIdx.x;
    int n0 = b * BUKSZ;
    int nvalid = min(BUKSZ, N - n0);
    int cnt = min(gcount[b], CAP);
    // inline exclusive prefix: sum_{i<b} min(gcount[i],CAP)  (b <= 512)
    int acc = 0;
    for (int i = tid; i < b; i += 256) acc += min(gcount[i], CAP);
    pref[tid] = acc;
    ldeg[tid] = 0;
    __syncthreads();
    #pragma unroll
    for (int off = 128; off; off >>= 1) {
        if (tid < off) pref[tid] += pref[tid + off];
        __syncthreads();
    }
    int base = pref[0] + n0;   // edges before + self-loops before
    for (int i = tid; i < cnt; i += 256) {
        int2 e = tmp[b * CAP + i];
        atomicAdd(&ldeg[e.y & 255], 1);
    }
    __syncthreads();
    int d = (tid < nvalid) ? (ldeg[tid] + 1) : 0;   // +1 self-loop
    lsc[tid] = d;
    __syncthreads();
    #pragma unroll
    for (int off = 1; off < 256; off <<= 1) {
        int u = (tid >= off) ? lsc[tid - off] : 0;
        __syncthreads();
        lsc[tid] += u;
        __syncthreads();
    }
    int excl = lsc[tid] - d;
    if (tid < nvalid) {
        int n = n0 + tid;
        offs[n] = base + excl;
        degi[n] = d;
        dinv[n] = rsqrtf((float)d);
        lcur[tid] = excl;
    }
    __syncthreads();
    for (int i = tid; i < cnt; i += 256) {
        int2 e = tmp[b * CAP + i];
        int nl = e.y & 255;
        int r = atomicAdd(&lcur[nl], 1);
        csr_src[base + r] = e.x;
    }
    __syncthreads();
    if (tid < nvalid) {
        int r = atomicAdd(&lcur[tid], 1);
        csr_src[base + r] = n0 + tid;   // self-loop
    }
}

// ---- GAT pull: 16 lanes/node, 4 nodes/wave, float4 gathers -----------------
// hscaled[n] = dinv[n] * relu(sum alpha*hp[src] + gat_b)
__global__ __launch_bounds__(256) void k_gat(const int* __restrict__ csr_src,
                                             const int* __restrict__ offs,
                                             const int* __restrict__ degi,
                                             const float* __restrict__ a_s,
                                             const float* __restrict__ a_d,
                                             const float* __restrict__ hp,
                                             const float* __restrict__ gat_b,
                                             const float* __restrict__ dinv,
                                             float* __restrict__ hscaled, int N) {
    __shared__ float ac[16][129];   // alpha cache, stride 129 -> distinct banks
    __shared__ int   si[16][129];   // src-index cache
    int tid = threadIdx.x;
    int g16 = tid >> 4;             // 0..15: (wave, node-subgroup)
    int cq  = tid & 15;             // col-quad within node
    int node = blockIdx.x * 16 + g16;   // N % 16 == 0
    int start = offs[node], deg = degi[node];
    int dcap = min(deg, 128);
    float adn = a_d[node];
    // phase A: 16-lane-group online softmax stats; stash raw e + src in LDS
    float m = -1e30f, ssum = 0.f;
    for (int p = cq; p < deg; p += 16) {
        int s = csr_src[start + p];
        float e = a_s[s] + adn;
        e = (e > 0.f) ? e : 0.2f * e;
        if (p < 128) { ac[g16][p] = e; si[g16][p] = s; }
        float mn = fmaxf(m, e);
        ssum = ssum * __expf(m - mn) + __expf(e - mn);
        m = mn;
    }
    #pragma unroll
    for (int off = 8; off; off >>= 1) {   // reduce within 16-lane group
        float om = __shfl_xor(m, off);
        float os = __shfl_xor(ssum, off);
        float mn = fmaxf(m, om);
        ssum = ssum * __expf(m - mn) + os * __expf(om - mn);
        m = mn;
    }
    float rinv = 1.0f / ssum;
    // convert stashed e -> alpha (same lanes that wrote convert their slots)
    for (int p = cq; p < dcap; p += 16)
        ac[g16][p] = __expf(ac[g16][p] - m) * rinv;
    // phase B: 8-deep float4 pipeline; 4 rows in flight per wave per slot
    const float4* __restrict__ hp4 = (const float4*)hp;
    float4 acc = make_float4(0.f, 0.f, 0.f, 0.f);
    for (int pp = 0; pp < dcap; pp += 8) {
        int s[8]; float w[8];
        #pragma unroll
        for (int i = 0; i < 8; ++i) {
            int q = pp + i;
            int qc = (q < dcap) ? q : (dcap - 1);
            s[i] = si[g16][qc];
            w[i] = (q < dcap) ? ac[g16][q] : 0.f;
        }
        float4 v[8];
        #pragma unroll
        for (int i = 0; i < 8; ++i) v[i] = hp4[(size_t)s[i] * 16 + cq];
        #pragma unroll
        for (int i = 0; i < 8; ++i) {
            acc.x = fmaf(w[i], v[i].x, acc.x);
            acc.y = fmaf(w[i], v[i].y, acc.y);
            acc.z = fmaf(w[i], v[i].z, acc.z);
            acc.w = fmaf(w[i], v[i].w, acc.w);
        }
    }
    for (int p = 128; p < deg; ++p) {   // deg > 128 overflow (essentially never)
        int s = csr_src[start + p];
        float e = a_s[s] + adn;
        e = (e > 0.f) ? e : 0.2f * e;
        float al = __expf(e - m) * rinv;
        float4 v = hp4[(size_t)s * 16 + cq];
        acc.x = fmaf(al, v.x, acc.x);
        acc.y = fmaf(al, v.y, acc.y);
        acc.z = fmaf(al, v.z, acc.z);
        acc.w = fmaf(al, v.w, acc.w);
    }
    float din = dinv[node];
    float4 gb = ((const float4*)gat_b)[cq];
    float4 o;
    o.x = din * fmaxf(acc.x + gb.x, 0.f);
    o.y = din * fmaxf(acc.y + gb.y, 0.f);
    o.z = din * fmaxf(acc.z + gb.z, 0.f);
    o.w = din * fmaxf(acc.w + gb.w, 0.f);
    ((float4*)hscaled)[(size_t)node * 16 + cq] = o;
}

// ---- GCN pull: 16 lanes/node, 4 nodes/wave, float4 gathers -----------------
// hagg[n] = dinv[n]*sum hscaled[src]
__global__ __launch_bounds__(256) void k_gcn(const int* __restrict__ csr_src,
                                             const int* __restrict__ offs,
                                             const int* __restrict__ degi,
                                             const float* __restrict__ dinv,
                                             const float* __restrict__ hscaled,
                                             float* __restrict__ hagg, int N) {
    int tid = threadIdx.x;
    int g16 = tid >> 4;
    int cq  = tid & 15;
    int node = blockIdx.x * 16 + g16;   // N % 16 == 0
    int start = offs[node], deg = degi[node];
    const float4* __restrict__ T4 = (const float4*)hscaled;
    float4 acc = make_float4(0.f, 0.f, 0.f, 0.f);
    for (int pp = 0; pp < deg; pp += 8) {
        int s[8];
        #pragma unroll
        for (int i = 0; i < 8; ++i) {
            int q = pp + i;
            int qc = (q < deg) ? q : (deg - 1);
            s[i] = csr_src[start + qc];
        }
        float4 v[8];
        #pragma unroll
        for (int i = 0; i < 8; ++i) v[i] = T4[(size_t)s[i] * 16 + cq];
        #pragma unroll
        for (int i = 0; i < 8; ++i) {
            if (pp + i < deg) {
                acc.x += v[i].x; acc.y += v[i].y;
                acc.z += v[i].z; acc.w += v[i].w;
            }
        }
    }
    float din = dinv[node];
    float4 o = make_float4(acc.x * din, acc.y * din, acc.z * din, acc.w * din);
    ((float4*)hagg)[(size_t)node * 16 + cq] = o;
}

// per-graph fused GEMM [*,64]@[64,128]+bias+relu + max-pool
// 512 thr: LDS-staged 16-node chunks, col=tid&127, 4 nodes/thread, float4 K
__global__ __launch_bounds__(512) void k_pool(const float* __restrict__ hagg,
                                              const float* __restrict__ gcn_w,
                                              const float* __restrict__ gcn_b,
                                              const int* __restrict__ gstart,
                                              float* __restrict__ g) {
    __shared__ float ws[D2 * D3];                 // 32 KB
    __shared__ __align__(16) float rows[16 * D2]; // 4 KB
    __shared__ float red[512];
    int tid = threadIdx.x;
    int gi = blockIdx.x;
    for (int i = tid; i < D2 * D3; i += 512) ws[i] = gcn_w[i];
    int ns = gstart[gi], ne = gstart[gi + 1];
    int col = tid & 127, grp = tid >> 7;   // 4 groups x 4 nodes
    float bias = gcn_b[col];
    float runmax = 0.f;   // relu floor; also handles empty graphs
    for (int base = ns; base < ne; base += 16) {
        int cnt = min(16, ne - base);
        __syncthreads();   // rows reuse + (first iter) ws ready
        for (int i = tid; i < cnt * D2; i += 512)
            rows[i] = hagg[(size_t)base * D2 + i];
        __syncthreads();
        int nb = grp * 4;
        float a0 = bias, a1 = bias, a2 = bias, a3 = bias;
        #pragma unroll 4
        for (int kc = 0; kc < 16; ++kc) {
            int k4 = kc * 4;
            float w0 = ws[(k4 + 0) * D3 + col];
            float w1v = ws[(k4 + 1) * D3 + col];
            float w2v = ws[(k4 + 2) * D3 + col];
            float w3v = ws[(k4 + 3) * D3 + col];
            float4 r0 = *reinterpret_cast<const float4*>(&rows[(nb + 0) * D2 + k4]);
            float4 r1 = *reinterpret_cast<const float4*>(&rows[(nb + 1) * D2 + k4]);
            float4 r2 = *reinterpret_cast<const float4*>(&rows[(nb + 2) * D2 + k4]);
            float4 r3 = *reinterpret_cast<const float4*>(&rows[(nb + 3) * D2 + k4]);
            a0 = fmaf(r0.x, w0, a0); a0 = fmaf(r0.y, w1v, a0);
            a0 = fmaf(r0.z, w2v, a0); a0 = fmaf(r0.w, w3v, a0);
            a1 = fmaf(r1.x, w0, a1); a1 = fmaf(r1.y, w1v, a1);
            a1 = fmaf(r1.z, w2v, a1); a1 = fmaf(r1.w, w3v, a1);
            a2 = fmaf(r2.x, w0, a2); a2 = fmaf(r2.y, w1v, a2);
            a2 = fmaf(r2.z, w2v, a2); a2 = fmaf(r2.w, w3v, a2);
            a3 = fmaf(r3.x, w0, a3); a3 = fmaf(r3.y, w1v, a3);
            a3 = fmaf(r3.z, w2v, a3); a3 = fmaf(r3.w, w3v, a3);
        }
        if (nb + 0 < cnt) runmax = fmaxf(runmax, a0);
        if (nb + 1 < cnt) runmax = fmaxf(runmax, a1);
        if (nb + 2 < cnt) runmax = fmaxf(runmax, a2);
        if (nb + 3 < cnt) runmax = fmaxf(runmax, a3);
    }
    red[tid] = runmax;
    __syncthreads();
    if (tid < 128) {
        float v = fmaxf(fmaxf(red[tid], red[tid + 128]),
                        fmaxf(red[tid + 256], red[tid + 384]));
        g[(size_t)gi * D3 + tid] = v;
    }
}

// ---- fused MLP head: z1 -> z2 -> out, all intermediates in LDS -------------
__global__ __launch_bounds__(512) void k_mlp(const float* __restrict__ g,
                                             const float* __restrict__ fc1_w,
                                             const float* __restrict__ fc1_b,
                                             const float* __restrict__ fc2_w,
                                             const float* __restrict__ fc2_b,
                                             const float* __restrict__ out_w,
                                             const float* __restrict__ out_b,
                                             float* __restrict__ out) {
    __shared__ float gs[4 * D3];     // 2 KB
    __shared__ float zs[4 * H1SZ];   // 8 KB
    __shared__ float z2s[4 * H2SZ];  // 4 KB
    __shared__ float red[8];
    int t = threadIdx.x;
    int g0 = blockIdx.x * 4;
    if (t < 4 * D3) gs[t] = g[(size_t)g0 * D3 + t];
    __syncthreads();
    // fc1
    {
        float bias = fc1_b[t];
        float a0 = bias, a1 = bias, a2 = bias, a3 = bias;
        for (int k = 0; k < D3; ++k) {
            float wv = fc1_w[k * H1SZ + t];
            a0 = fmaf(gs[k], wv, a0);
            a1 = fmaf(gs[D3 + k], wv, a1);
            a2 = fmaf(gs[2 * D3 + k], wv, a2);
            a3 = fmaf(gs[3 * D3 + k], wv, a3);
        }
        zs[0 * H1SZ + t] = fmaxf(a0, 0.f);
        zs[1 * H1SZ + t] = fmaxf(a1, 0.f);
        zs[2 * H1SZ + t] = fmaxf(a2, 0.f);
        zs[3 * H1SZ + t] = fmaxf(a3, 0.f);
    }
    __syncthreads();
    // fc2: thread t -> col t&255, graphs {2*(t>>8), 2*(t>>8)+1}
    {
        int ct = t & 255, jp = t >> 8;
        float bias = fc2_b[ct];
        float a0 = bias, a1 = bias;
        const float* zA = &zs[(2 * jp) * H1SZ];
        const float* zB = &zs[(2 * jp + 1) * H1SZ];
        for (int k = 0; k < H1SZ; ++k) {
            float wv = fc2_w[k * H2SZ + ct];
            a0 = fmaf(zA[k], wv, a0);
            a1 = fmaf(zB[k], wv, a1);
        }
        z2s[(2 * jp) * H2SZ + ct] = fmaxf(a0, 0.f);
        z2s[(2 * jp + 1) * H2SZ + ct] = fmaxf(a1, 0.f);
    }
    __syncthreads();
    // out: graph j = t>>7, col c2 = t&127 (2 cols per thread)
    {
        int j = t >> 7, c2 = t & 127;
        float p = z2s[j * H2SZ + c2] * out_w[c2]
                + z2s[j * H2SZ + c2 + 128] * out_w[c2 + 128];
        #pragma unroll
        for (int off = 32; off; off >>= 1) p += __shfl_down(p, off);
        int lane = t & 63, w8 = t >> 6;
        if (lane == 0) red[w8] = p;
        __syncthreads();
        if (t < 4) out[g0 + t] = red[2 * t] + red[2 * t + 1] + out_b[0];
    }
}

extern "C" void kernel_launch(void* const* d_in, const int* in_sizes, int n_in,
                              void* d_out, int out_size, void* d_ws, size_t ws_size,
                              hipStream_t stream) {
    const float* x        = (const float*)d_in[0];
    const int*   ei       = (const int*)d_in[1];
    // d_in[2] = edge_intra (unused by reference)
    const int*   batch    = (const int*)d_in[3];
    // d_in[4] = num_graphs scalar (== out_size)
    const float* w1       = (const float*)d_in[5];
    const float* b1       = (const float*)d_in[6];
    const float* w2       = (const float*)d_in[7];
    const float* b2       = (const float*)d_in[8];
    const float* gat_w    = (const float*)d_in[9];
    const float* att_src  = (const float*)d_in[10];
    const float* att_dst  = (const float*)d_in[11];
    const float* gat_b    = (const float*)d_in[12];
    const float* gcn_w    = (const float*)d_in[13];
    const float* gcn_b    = (const float*)d_in[14];
    const float* fc1_w    = (const float*)d_in[15];
    const float* fc1_b    = (const float*)d_in[16];
    const float* fc2_w    = (const float*)d_in[17];
    const float* fc2_b    = (const float*)d_in[18];
    const float* out_w    = (const float*)d_in[19];
    const float* out_b    = (const float*)d_in[20];
    float* out = (float*)d_out;

    const int N = in_sizes[0] / F_IN;
    const int E = in_sizes[1] / 2;
    const int M = E + N;             // edges incl. self-loops
    const int G = out_size;
    const int NBUK = (N + BUKSZ - 1) / BUKSZ;
    const int embB   = N / 32;
    const int partB  = (E + PART_CH - 1) / PART_CH;
    const int boundB = (N + 255) / 256;

    // workspace carve-up
    char* p = (char*)d_ws;
    size_t off = 0;
    auto alloc = [&](size_t bytes) { void* q = p + off; off += (bytes + 255) & ~(size_t)255; return q; };
    int2*  tmp     = (int2*)alloc((size_t)NBUK * CAP * 8);   // 16 MB
    int*   csr_src = (int*)alloc((size_t)M * 4);
    float* hp      = (float*)alloc((size_t)N * D2 * 4);      // row-major [N][64]
    float* hscaled = (float*)alloc((size_t)N * D2 * 4);      // row-major [N][64]
    float* hagg    = (float*)alloc((size_t)N * D2 * 4);      // row-major [N][64]
    int*   offs    = (int*)alloc((size_t)N * 4);
    int*   degi    = (int*)alloc((size_t)N * 4);
    float* dinv    = (float*)alloc((size_t)N * 4);
    float* a_s     = (float*)alloc((size_t)N * 4);
    float* a_d     = (float*)alloc((size_t)N * 4);
    int*   gcount  = (int*)alloc((size_t)NBUK * 4);
    int*   gstart  = (int*)alloc((size_t)(G + 1) * 4);
    float* g       = (float*)alloc((size_t)G * D3 * 4);
    float* v_src   = (float*)alloc(D2 * 4);
    float* v_dst   = (float*)alloc(D2 * 4);

    hipMemsetAsync(gcount, 0, (size_t)NBUK * 4, stream);

    k_vecproj<<<1, 64, 0, stream>>>(gat_w, att_src, att_dst, v_src, v_dst);
    // fused: node embedding | edge partition | graph bounds
    k_fused<<<embB + partB + boundB, 256, 0, stream>>>(
        x, w1, b1, w2, b2, gat_w, v_src, v_dst, hp, a_s, a_d,
        ei, gcount, tmp, batch, gstart, N, E, NBUK, G, embB, partB);
    // CSR finalize (inline prefix over gcount)
    k_build<<<NBUK, 256, 0, stream>>>(tmp, gcount, offs, degi, dinv, csr_src, N);
    // pull-mode aggregations: 16 lanes/node float4 pipelines (4 rows/slot)
    k_gat<<<N / 16, 256, 0, stream>>>(csr_src, offs, degi, a_s, a_d, hp,
                                      gat_b, dinv, hscaled, N);
    k_gcn<<<N / 16, 256, 0, stream>>>(csr_src, offs, degi, dinv, hscaled, hagg, N);
    // per-graph GEMM + relu + max-pool (LDS-tiled)
    k_pool<<<G, 512, 0, stream>>>(hagg, gcn_w, gcn_b, gstart, g);
    // fused MLP head (fc1 -> fc2 -> out in one kernel)
    k_mlp<<<G / 4, 512, 0, stream>>>(g, fc1_w, fc1_b, fc2_w, fc2_b, out_w, out_b, out);
}